// Round 3
// baseline (222.075 us; speedup 1.0000x reference)
//
#include <hip/hip_runtime.h>

#define DEVI static __device__ __forceinline__

typedef unsigned short u16;
typedef unsigned int u32;
typedef __attribute__((ext_vector_type(8))) __bf16 bf16x8;
typedef __attribute__((ext_vector_type(8))) short short8;
typedef __attribute__((ext_vector_type(4))) float f32x4;

DEVI u16 f2bf(float f) {
  union { float f; u32 u; } v; v.f = f;
  u32 r = v.u + 0x7fffu + ((v.u >> 16) & 1u);  // RNE
  return (u16)(r >> 16);
}

DEVI u16 bfc(float f) {
  union { __bf16 b; u16 u; } v; v.b = (__bf16)f; return v.u;
}

DEVI void gload16(const void* g, void* l) {
  __builtin_amdgcn_global_load_lds(
      (const __attribute__((address_space(1))) void*)g,
      (__attribute__((address_space(3))) void*)l,
      16, 0, 0);
}

// ---------------- fp32 -> bf16 convert (vectorized) ----------------
__global__ void k_cvt(const float* __restrict__ in, u16* __restrict__ out, int n4) {
  int i = blockIdx.x * blockDim.x + threadIdx.x;
  if (i >= n4) return;
  const float4 v = reinterpret_cast<const float4*>(in)[i];
  ushort4 o;
  o.x = f2bf(v.x); o.y = f2bf(v.y); o.z = f2bf(v.z); o.w = f2bf(v.w);
  reinterpret_cast<ushort4*>(out)[i] = o;
}

// ---------------- mask -> additive float bias ----------------
__global__ void k_maskbias(const int* __restrict__ m, float* __restrict__ bias, int n) {
  int i = blockIdx.x * blockDim.x + threadIdx.x;
  if (i < n) bias[i] = (m[i] == 1) ? 0.f : -1e30f;
}

// ---------------- W[k][n] fp32 -> Wt[n][k] bf16 (1024x1024) ----------------
__global__ void k_transcvt(const float* __restrict__ W, u16* __restrict__ Wt) {
  __shared__ float tl[32][33];
  const int n0 = blockIdx.x * 32, k0 = blockIdx.y * 32;
  const int tx = threadIdx.x, ty = threadIdx.y;
#pragma unroll
  for (int r = ty; r < 32; r += 8)
    tl[r][tx] = W[(size_t)(k0 + r) * 1024 + n0 + tx];
  __syncthreads();
#pragma unroll
  for (int r = ty; r < 32; r += 8)
    Wt[(size_t)(n0 + r) * 1024 + k0 + tx] = f2bf(tl[tx][r]);
}

// ---------------- GEMM: C[M][N] = (A[M][K](bf16) * Bt[N][K](bf16) + bias) * scale ----
// 128x128 tile, BK=32, 4 waves (2x2), each wave 4x4 16x16x32 MFMA frags.
// If Vt != nullptr and z == 2, writes transposed bf16 Vt[(r>>11)*1024 + c][r&2047]
// instead of row-major C (for attention's direct V^T fragment loads).
DEVI void store1(u16* C, size_t i, float v) { C[i] = f2bf(v); }
DEVI void store1(float* C, size_t i, float v) { C[i] = v; }

template <typename OutT>
__global__ __launch_bounds__(256, 2) void k_gemm_bt(
    const u16* __restrict__ Abase, long aZ,
    const u16* __restrict__ Btbase, long bZ,
    const float* __restrict__ bias0, const float* __restrict__ bias1,
    const float* __restrict__ bias2,
    float s0, float s1, float s2,
    OutT* __restrict__ Cbase, long cZ, u16* __restrict__ Vt,
    int M, int N, int K) {
  const int z = blockIdx.z;
  const u16* A  = Abase  + (size_t)z * aZ;
  const u16* Bt = Btbase + (size_t)z * bZ;
  OutT* C = Cbase + (size_t)z * cZ;
  const float* bias = (z == 0) ? bias0 : ((z == 1) ? bias1 : bias2);
  const float scl = (z == 0) ? s0 : ((z == 1) ? s1 : s2);

  __shared__ u16 lsA[128 * 32];
  __shared__ u16 lsB[128 * 32];

  const int t = threadIdx.x;
  const int w = t >> 6, ln = t & 63;
  const int l15 = ln & 15, lhi = ln >> 4;
  const int wr = w >> 1, wc = w & 1;
  const int m0 = blockIdx.x * 128, n0 = blockIdx.y * 128;

  f32x4 acc[4][4] = {};

  for (int kt = 0; kt < K; kt += 32) {
#pragma unroll
    for (int i = 0; i < 2; ++i) {
      const int li = i * 256 + t;
      const int row = li >> 2, cb = (li & 3) << 3;
      gload16(A + (size_t)(m0 + row) * K + kt + cb,
              (char*)lsA + (i * 256 + w * 64) * 16);
      gload16(Bt + (size_t)(n0 + row) * K + kt + cb,
              (char*)lsB + (i * 256 + w * 64) * 16);
    }
    __syncthreads();

    bf16x8 af[4], bf_[4];
#pragma unroll
    for (int m = 0; m < 4; ++m)
      af[m] = *reinterpret_cast<const bf16x8*>(
          &lsA[(wr * 64 + m * 16 + l15) * 32 + lhi * 8]);
#pragma unroll
    for (int n = 0; n < 4; ++n)
      bf_[n] = *reinterpret_cast<const bf16x8*>(
          &lsB[(wc * 64 + n * 16 + l15) * 32 + lhi * 8]);
#pragma unroll
    for (int m = 0; m < 4; ++m)
#pragma unroll
      for (int n = 0; n < 4; ++n)
        acc[m][n] = __builtin_amdgcn_mfma_f32_16x16x32_bf16(af[m], bf_[n], acc[m][n], 0, 0, 0);
    __syncthreads();
  }

  if (Vt != nullptr && z == 2) {
    // transposed write: Vt[(b*1024 + c)][s], 4 consecutive tokens per quad
#pragma unroll
    for (int n = 0; n < 4; ++n) {
      const int c = n0 + wc * 64 + n * 16 + l15;
      const float bv = bias[c];
#pragma unroll
      for (int m = 0; m < 4; ++m) {
        const int r = m0 + wr * 64 + m * 16 + lhi * 4;
        ushort4 s4;
#pragma unroll
        for (int j = 0; j < 4; ++j) ((u16*)&s4)[j] = f2bf(acc[m][n][j] + bv);
        *reinterpret_cast<ushort4*>(
            &Vt[((size_t)((r >> 11) * 1024 + c)) * 2048 + (r & 2047)]) = s4;
      }
    }
    return;
  }

#pragma unroll
  for (int n = 0; n < 4; ++n) {
    const int c = n0 + wc * 64 + n * 16 + l15;
    const float bv = bias[c];
#pragma unroll
    for (int m = 0; m < 4; ++m)
#pragma unroll
      for (int j = 0; j < 4; ++j) {
        const int r = m0 + wr * 64 + m * 16 + lhi * 4 + j;
        store1(C, (size_t)r * N + c, (acc[m][n][j] + bv) * scl);
      }
  }
}

// ---------------- flash attention (swapped QK^T, direct-global K/V frags) ----------
// grid (S/128, NH, B), 256 threads = 4 waves, each wave owns 32 q-rows.
// Q pre-scaled by 0.125*log2(e). K row-major [B*S][H]; Vt transposed [B*H][S].
// K/V per head = 256KB -> L2-resident; no LDS staging, no barriers.
__global__ __launch_bounds__(256, 2) void k_attn(
    const u16* __restrict__ Q, const u16* __restrict__ K, const u16* __restrict__ Vt,
    const float* __restrict__ MB, u16* __restrict__ O) {
  __shared__ u16 lsPt[4][32][72];  // per-wave P[q_local][key] bf16

  const int t = threadIdx.x, w = t >> 6, ln = t & 63;
  const int l15 = ln & 15, lhi = ln >> 4;
  const int qt = blockIdx.x, h = blockIdx.y, b = blockIdx.z;
  const size_t rowQ = (size_t)b * 2048 + qt * 128 + w * 32;
  const int hc = h * 64;

  // Q fragments (B-operand): row q = mq*16+l15, k-cols = ks*32+lhi*8
  bf16x8 qb[2][2];
#pragma unroll
  for (int mq = 0; mq < 2; ++mq)
#pragma unroll
    for (int ks = 0; ks < 2; ++ks)
      qb[mq][ks] = *reinterpret_cast<const bf16x8*>(
          &Q[(rowQ + mq * 16 + l15) * 1024 + hc + ks * 32 + lhi * 8]);

  // base rows for direct fragment loads
  const u16* Kb = K + ((size_t)b * 2048 + l15) * 1024 + hc + lhi * 8;       // + key*1024
  const u16* Vb = Vt + ((size_t)(b * 1024 + hc) + l15) * 2048 + lhi * 8;    // + d*2048 + key

  f32x4 o[4][2] = {};  // O^T[d-frag nd][q-frag mq]
  float mrow[2] = {-1e30f, -1e30f}, lsum[2] = {0.f, 0.f};

  for (int nt = 0; nt < 2048; nt += 64) {
    // K fragments (A-operand): row = key = nk*16+l15, cols d = ks*32+lhi*8
    bf16x8 kf[4][2];
#pragma unroll
    for (int nk = 0; nk < 4; ++nk)
#pragma unroll
      for (int ks = 0; ks < 2; ++ks)
        kf[nk][ks] = *reinterpret_cast<const bf16x8*>(
            &Kb[(size_t)(nt + nk * 16) * 1024 + ks * 32]);

    // V^T fragments (A-operand): row = d = nd*16+l15, cols key = ks*32+lhi*8
    bf16x8 vf[4][2];
#pragma unroll
    for (int nd = 0; nd < 4; ++nd)
#pragma unroll
      for (int ks = 0; ks < 2; ++ks)
        vf[nd][ks] = *reinterpret_cast<const bf16x8*>(
            &Vb[(size_t)(nd * 16) * 2048 + nt + ks * 32]);

    // S^T = K Q^T : st[nk][mq], row = key = nk*16+lhi*4+j, col = q = mq*16+l15
    f32x4 st[4][2] = {};
    __builtin_amdgcn_s_setprio(1);
#pragma unroll
    for (int nk = 0; nk < 4; ++nk)
#pragma unroll
      for (int ks = 0; ks < 2; ++ks) {
        st[nk][0] = __builtin_amdgcn_mfma_f32_16x16x32_bf16(kf[nk][ks], qb[0][ks], st[nk][0], 0, 0, 0);
        st[nk][1] = __builtin_amdgcn_mfma_f32_16x16x32_bf16(kf[nk][ks], qb[1][ks], st[nk][1], 0, 0, 0);
      }
    __builtin_amdgcn_s_setprio(0);

    // additive key-padding bias
#pragma unroll
    for (int nk = 0; nk < 4; ++nk) {
      const f32x4 bv = *reinterpret_cast<const f32x4*>(&MB[b * 2048 + nt + nk * 16 + lhi * 4]);
#pragma unroll
      for (int mq = 0; mq < 2; ++mq)
#pragma unroll
        for (int j = 0; j < 4; ++j)
          st[nk][mq][j] += bv[j];
    }

    // online softmax: per lane, column q = mq*16+l15; reduce 16 in-reg + xor16/xor32
    float al[2];
#pragma unroll
    for (int mq = 0; mq < 2; ++mq) {
      float tm = st[0][mq][0];
#pragma unroll
      for (int nk = 0; nk < 4; ++nk)
#pragma unroll
        for (int j = 0; j < 4; ++j) tm = fmaxf(tm, st[nk][mq][j]);
      tm = fmaxf(tm, __shfl_xor(tm, 16, 64));
      tm = fmaxf(tm, __shfl_xor(tm, 32, 64));
      const float mn = fmaxf(mrow[mq], tm);
      al[mq] = __builtin_amdgcn_exp2f(mrow[mq] - mn);
      mrow[mq] = mn;
      float rs = 0.f;
#pragma unroll
      for (int nk = 0; nk < 4; ++nk)
#pragma unroll
        for (int j = 0; j < 4; ++j) {
          const float p = __builtin_amdgcn_exp2f(st[nk][mq][j] - mn);
          st[nk][mq][j] = p;
          rs += p;
        }
      rs += __shfl_xor(rs, 16, 64);
      rs += __shfl_xor(rs, 32, 64);
      lsum[mq] = lsum[mq] * al[mq] + rs;
    }
    if (__any((al[0] != 1.f) || (al[1] != 1.f))) {
#pragma unroll
      for (int nd = 0; nd < 4; ++nd)
#pragma unroll
        for (int mq = 0; mq < 2; ++mq)
#pragma unroll
          for (int j = 0; j < 4; ++j) o[nd][mq][j] *= al[mq];
    }

    // P -> LDS (bf16, vectorized b64 writes; per-wave buffer, in-order DS pipe)
#pragma unroll
    for (int mq = 0; mq < 2; ++mq)
#pragma unroll
      for (int nk = 0; nk < 4; ++nk) {
        ushort4 pk;
        pk.x = bfc(st[nk][mq][0]); pk.y = bfc(st[nk][mq][1]);
        pk.z = bfc(st[nk][mq][2]); pk.w = bfc(st[nk][mq][3]);
        *reinterpret_cast<ushort4*>(&lsPt[w][mq * 16 + l15][nk * 16 + lhi * 4]) = pk;
      }

    // O^T += V^T P^T
    __builtin_amdgcn_s_setprio(1);
#pragma unroll
    for (int ks = 0; ks < 2; ++ks) {
      bf16x8 pb[2];
#pragma unroll
      for (int mq = 0; mq < 2; ++mq)
        pb[mq] = *reinterpret_cast<const bf16x8*>(
            &lsPt[w][mq * 16 + l15][ks * 32 + lhi * 8]);
#pragma unroll
      for (int nd = 0; nd < 4; ++nd) {
        o[nd][0] = __builtin_amdgcn_mfma_f32_16x16x32_bf16(vf[nd][ks], pb[0], o[nd][0], 0, 0, 0);
        o[nd][1] = __builtin_amdgcn_mfma_f32_16x16x32_bf16(vf[nd][ks], pb[1], o[nd][1], 0, 0, 0);
      }
    }
    __builtin_amdgcn_s_setprio(0);
  }

  // epilogue: O[q][d], d = nd*16+lhi*4+j, q = mq*16+l15
#pragma unroll
  for (int mq = 0; mq < 2; ++mq) {
    const float inv = 1.f / lsum[mq];
#pragma unroll
    for (int nd = 0; nd < 4; ++nd) {
      ushort4 s4;
      s4.x = bfc(o[nd][mq][0] * inv); s4.y = bfc(o[nd][mq][1] * inv);
      s4.z = bfc(o[nd][mq][2] * inv); s4.w = bfc(o[nd][mq][3] * inv);
      *reinterpret_cast<ushort4*>(
          &O[(rowQ + mq * 16 + l15) * 1024 + hc + nd * 16 + lhi * 4]) = s4;
    }
  }
}

extern "C" void kernel_launch(void* const* d_in, const int* in_sizes, int n_in,
                              void* d_out, int out_size, void* d_ws, size_t ws_size,
                              hipStream_t stream) {
  const float* x_q = (const float*)d_in[0];
  const float* x_k = (const float*)d_in[1];
  const float* x_v = (const float*)d_in[2];
  const int*   msk = (const int*)d_in[3];
  const float* Wq  = (const float*)d_in[4];
  const float* bq  = (const float*)d_in[5];
  const float* Wk  = (const float*)d_in[6];
  const float* bk  = (const float*)d_in[7];
  const float* Wv  = (const float*)d_in[8];
  const float* bv  = (const float*)d_in[9];
  const float* Wo  = (const float*)d_in[10];
  const float* bo  = (const float*)d_in[11];

  const size_t NTOK = 4096, H = 1024;
  u16* xbf  = (u16*)d_ws;            // 3 * 4096*1024 bf16
  u16* wt   = xbf + 3 * NTOK * H;    // 4 * 1024*1024 bf16 (transposed weights)
  u16* qkv  = wt  + 4 * H * H;       // Q,K row-major; V slot holds Vt (transposed)
  u16* aout = qkv + 3 * NTOK * H;    // 4096*1024 bf16
  float* mb = (float*)(aout + NTOK * H);  // 4096 floats
  u16* vtb  = qkv + 2 * NTOK * H;    // Vt[b*1024 + c][s] (reuses V slot)

  k_cvt<<<dim3(4096), dim3(256), 0, stream>>>(x_q, xbf,              1048576);
  k_cvt<<<dim3(4096), dim3(256), 0, stream>>>(x_k, xbf + NTOK * H,   1048576);
  k_cvt<<<dim3(4096), dim3(256), 0, stream>>>(x_v, xbf + 2 * NTOK * H, 1048576);
  k_maskbias<<<dim3(16), dim3(256), 0, stream>>>(msk, mb, 4096);
  k_transcvt<<<dim3(32, 32), dim3(32, 8), 0, stream>>>(Wq, wt);
  k_transcvt<<<dim3(32, 32), dim3(32, 8), 0, stream>>>(Wk, wt + H * H);
  k_transcvt<<<dim3(32, 32), dim3(32, 8), 0, stream>>>(Wv, wt + 2 * H * H);
  k_transcvt<<<dim3(32, 32), dim3(32, 8), 0, stream>>>(Wo, wt + 3 * H * H);

  // Q,K,V = x{q,k,v} @ W{q,k,v} + b{q,k,v}; Q scaled by 0.125*log2(e) for exp2 softmax
  // z==2 (V) writes transposed into vtb.
  const float qscale = 0.125f * 1.4426950408889634f;
  k_gemm_bt<u16><<<dim3(32, 8, 3), dim3(256), 0, stream>>>(
      xbf, (long)(NTOK * H), wt, (long)(H * H), bq, bk, bv,
      qscale, 1.f, 1.f,
      qkv, (long)(NTOK * H), vtb, 4096, 1024, 1024);

  // attention
  k_attn<<<dim3(16, 16, 2), dim3(256), 0, stream>>>(
      qkv, qkv + NTOK * H, vtb, mb, aout);

  // out = attn_out @ Wo + bo  (fp32 output)
  k_gemm_bt<float><<<dim3(32, 8, 1), dim3(256), 0, stream>>>(
      aout, 0L, wt + 3 * H * H, 0L, bo, bo, bo,
      1.f, 1.f, 1.f,
      (float*)d_out, 0L, nullptr, 4096, 1024, 1024);
}

// Round 4
// 156.944 us; speedup vs baseline: 1.4150x; 1.4150x over previous
//
#include <hip/hip_runtime.h>

#define DEVI static __device__ __forceinline__

typedef unsigned short u16;
typedef unsigned int u32;
typedef __attribute__((ext_vector_type(8))) __bf16 bf16x8;
typedef __attribute__((ext_vector_type(8))) short short8;
typedef __attribute__((ext_vector_type(4))) float f32x4;

DEVI u16 f2bf(float f) {
  union { float f; u32 u; } v; v.f = f;
  u32 r = v.u + 0x7fffu + ((v.u >> 16) & 1u);  // RNE
  return (u16)(r >> 16);
}

DEVI u16 bfc(float f) {
  union { __bf16 b; u16 u; } v; v.b = (__bf16)f; return v.u;
}

DEVI void gload16(const void* g, void* l) {
  __builtin_amdgcn_global_load_lds(
      (const __attribute__((address_space(1))) void*)g,
      (__attribute__((address_space(3))) void*)l,
      16, 0, 0);
}

// ---------------- fp32 -> bf16 convert (vectorized) ----------------
__global__ void k_cvt(const float* __restrict__ in, u16* __restrict__ out, int n4) {
  int i = blockIdx.x * blockDim.x + threadIdx.x;
  if (i >= n4) return;
  const float4 v = reinterpret_cast<const float4*>(in)[i];
  ushort4 o;
  o.x = f2bf(v.x); o.y = f2bf(v.y); o.z = f2bf(v.z); o.w = f2bf(v.w);
  reinterpret_cast<ushort4*>(out)[i] = o;
}

// ---------------- mask -> additive float bias ----------------
__global__ void k_maskbias(const int* __restrict__ m, float* __restrict__ bias, int n) {
  int i = blockIdx.x * blockDim.x + threadIdx.x;
  if (i < n) bias[i] = (m[i] == 1) ? 0.f : -1e30f;
}

// ---------------- W[k][n] fp32 -> Wt[n][k] bf16 (1024x1024) ----------------
__global__ void k_transcvt(const float* __restrict__ W, u16* __restrict__ Wt) {
  __shared__ float tl[32][33];
  const int n0 = blockIdx.x * 32, k0 = blockIdx.y * 32;
  const int tx = threadIdx.x, ty = threadIdx.y;
#pragma unroll
  for (int r = ty; r < 32; r += 8)
    tl[r][tx] = W[(size_t)(k0 + r) * 1024 + n0 + tx];
  __syncthreads();
#pragma unroll
  for (int r = ty; r < 32; r += 8)
    Wt[(size_t)(n0 + r) * 1024 + k0 + tx] = f2bf(tl[tx][r]);
}

// ---------------- GEMM: C[M][N] = (A[M][K](bf16) * Bt[N][K](bf16) + bias) * scale ----
DEVI void store1(u16* C, size_t i, float v) { C[i] = f2bf(v); }
DEVI void store1(float* C, size_t i, float v) { C[i] = v; }

template <typename OutT>
__global__ __launch_bounds__(256, 2) void k_gemm_bt(
    const u16* __restrict__ Abase, long aZ,
    const u16* __restrict__ Btbase, long bZ,
    const float* __restrict__ bias0, const float* __restrict__ bias1,
    const float* __restrict__ bias2,
    float s0, float s1, float s2,
    OutT* __restrict__ Cbase, long cZ, u16* __restrict__ Vt,
    int M, int N, int K) {
  const int z = blockIdx.z;
  const u16* A  = Abase  + (size_t)z * aZ;
  const u16* Bt = Btbase + (size_t)z * bZ;
  OutT* C = Cbase + (size_t)z * cZ;
  const float* bias = (z == 0) ? bias0 : ((z == 1) ? bias1 : bias2);
  const float scl = (z == 0) ? s0 : ((z == 1) ? s1 : s2);

  __shared__ u16 lsA[128 * 32];
  __shared__ u16 lsB[128 * 32];

  const int t = threadIdx.x;
  const int w = t >> 6, ln = t & 63;
  const int l15 = ln & 15, lhi = ln >> 4;
  const int wr = w >> 1, wc = w & 1;
  const int m0 = blockIdx.x * 128, n0 = blockIdx.y * 128;

  f32x4 acc[4][4] = {};

  for (int kt = 0; kt < K; kt += 32) {
#pragma unroll
    for (int i = 0; i < 2; ++i) {
      const int li = i * 256 + t;
      const int row = li >> 2, cb = (li & 3) << 3;
      gload16(A + (size_t)(m0 + row) * K + kt + cb,
              (char*)lsA + (i * 256 + w * 64) * 16);
      gload16(Bt + (size_t)(n0 + row) * K + kt + cb,
              (char*)lsB + (i * 256 + w * 64) * 16);
    }
    __syncthreads();

    bf16x8 af[4], bf_[4];
#pragma unroll
    for (int m = 0; m < 4; ++m)
      af[m] = *reinterpret_cast<const bf16x8*>(
          &lsA[(wr * 64 + m * 16 + l15) * 32 + lhi * 8]);
#pragma unroll
    for (int n = 0; n < 4; ++n)
      bf_[n] = *reinterpret_cast<const bf16x8*>(
          &lsB[(wc * 64 + n * 16 + l15) * 32 + lhi * 8]);
#pragma unroll
    for (int m = 0; m < 4; ++m)
#pragma unroll
      for (int n = 0; n < 4; ++n)
        acc[m][n] = __builtin_amdgcn_mfma_f32_16x16x32_bf16(af[m], bf_[n], acc[m][n], 0, 0, 0);
    __syncthreads();
  }

  if (Vt != nullptr && z == 2) {
    // transposed write: Vt[(b*1024 + c)][s], 4 consecutive tokens per quad
#pragma unroll
    for (int n = 0; n < 4; ++n) {
      const int c = n0 + wc * 64 + n * 16 + l15;
      const float bv = bias[c];
#pragma unroll
      for (int m = 0; m < 4; ++m) {
        const int r = m0 + wr * 64 + m * 16 + lhi * 4;
        ushort4 s4;
#pragma unroll
        for (int j = 0; j < 4; ++j) ((u16*)&s4)[j] = f2bf(acc[m][n][j] + bv);
        *reinterpret_cast<ushort4*>(
            &Vt[((size_t)((r >> 11) * 1024 + c)) * 2048 + (r & 2047)]) = s4;
      }
    }
    return;
  }

#pragma unroll
  for (int n = 0; n < 4; ++n) {
    const int c = n0 + wc * 64 + n * 16 + l15;
    const float bv = bias[c];
#pragma unroll
    for (int m = 0; m < 4; ++m)
#pragma unroll
      for (int j = 0; j < 4; ++j) {
        const int r = m0 + wr * 64 + m * 16 + lhi * 4 + j;
        store1(C, (size_t)r * N + c, (acc[m][n][j] + bv) * scl);
      }
  }
}

// ---------------- flash attention ----------------
// flat grid 512, XCD-grouped: each XCD owns 4 (b,h) pairs x 16 qt blocks, so
// per-XCD hot K/Vt = 2MB < 4MB L2. 256 threads = 4 waves, 32 q-rows/wave.
// Double-buffered LDS staging: load tile t+1 to regs early, ds_write after
// compute (vmcnt covered by compute), ONE barrier per tile.
// Q pre-scaled by 0.125*log2(e). K row-major [B*S][H]; Vt transposed [B*H][S].
__global__ __launch_bounds__(256, 2) void k_attn(
    const u16* __restrict__ Q, const u16* __restrict__ K, const u16* __restrict__ Vt,
    const float* __restrict__ MB, u16* __restrict__ O) {
  __shared__ u16 lsK[2][64][72];   // [buf][key][d]   pad-72: conflict-minimal b128
  __shared__ u16 lsV[2][64][72];   // [buf][d][key]
  __shared__ u16 lsPt[4][32][72];  // per-wave P[q_local][key] bf16

  const int t = threadIdx.x, w = t >> 6, ln = t & 63;
  const int l15 = ln & 15, lhi = ln >> 4;
  // XCD-grouped block mapping (bijection; perf-only heuristic)
  const int fid = blockIdx.x;            // 0..511
  const int xcd = fid & 7, slot = fid >> 3;
  const int pair = xcd * 4 + (slot >> 4);  // 0..31
  const int qt = slot & 15;
  const int h = pair & 15, b = pair >> 4;

  const size_t rowQ = (size_t)b * 2048 + qt * 128 + w * 32;
  const int hc = h * 64;

  // staging geometry: chunk ci = i*256+t covers row=ci>>3 (0..63), col8=(ci&7)*8
  const int srow = t >> 3, scol = (t & 7) << 3;
  const u16* Kg = K + ((size_t)b * 2048 + srow) * 1024 + hc + scol;       // +nt*1024
  const u16* Vg = Vt + ((size_t)(b * 1024 + hc) + srow) * 2048 + scol;    // +nt

  // Q fragments (B-operand): row q = mq*16+l15, k-cols = ks*32+lhi*8
  bf16x8 qb[2][2];
#pragma unroll
  for (int mq = 0; mq < 2; ++mq)
#pragma unroll
    for (int ks = 0; ks < 2; ++ks)
      qb[mq][ks] = *reinterpret_cast<const bf16x8*>(
          &Q[(rowQ + mq * 16 + l15) * 1024 + hc + ks * 32 + lhi * 8]);

  f32x4 o[4][2] = {};  // O^T[d-frag nd][q-frag mq]
  float mrow[2] = {-1e30f, -1e30f}, lsum[2] = {0.f, 0.f};

  // prologue: stage tile 0 into buf 0
  short8 rk0, rk1, rv0, rv1;
  rk0 = *reinterpret_cast<const short8*>(Kg);
  rk1 = *reinterpret_cast<const short8*>(Kg + 32 * 1024);
  rv0 = *reinterpret_cast<const short8*>(Vg);
  rv1 = *reinterpret_cast<const short8*>(Vg + 32 * 2048);
  *reinterpret_cast<short8*>(&lsK[0][srow][scol]) = rk0;
  *reinterpret_cast<short8*>(&lsK[0][32 + srow][scol]) = rk1;
  *reinterpret_cast<short8*>(&lsV[0][srow][scol]) = rv0;
  *reinterpret_cast<short8*>(&lsV[0][32 + srow][scol]) = rv1;
  __syncthreads();

  int cur = 0;
  for (int nt = 0; nt < 2048; nt += 64) {
    // issue next tile's global loads early (latency hides under compute)
    const int ntn = (nt + 64 < 2048) ? nt + 64 : 0;
    rk0 = *reinterpret_cast<const short8*>(Kg + (size_t)ntn * 1024);
    rk1 = *reinterpret_cast<const short8*>(Kg + (size_t)(ntn + 32) * 1024);
    rv0 = *reinterpret_cast<const short8*>(Vg + ntn);
    rv1 = *reinterpret_cast<const short8*>(Vg + 32 * 2048 + ntn);

    // S^T = K Q^T : st[nk][mq], row = key = nk*16+lhi*4+j, col = q = mq*16+l15
    f32x4 st[4][2] = {};
    __builtin_amdgcn_s_setprio(1);
#pragma unroll
    for (int nk = 0; nk < 4; ++nk)
#pragma unroll
      for (int ks = 0; ks < 2; ++ks) {
        const bf16x8 kb = *reinterpret_cast<const bf16x8*>(
            &lsK[cur][nk * 16 + l15][ks * 32 + lhi * 8]);
        st[nk][0] = __builtin_amdgcn_mfma_f32_16x16x32_bf16(kb, qb[0][ks], st[nk][0], 0, 0, 0);
        st[nk][1] = __builtin_amdgcn_mfma_f32_16x16x32_bf16(kb, qb[1][ks], st[nk][1], 0, 0, 0);
      }
    __builtin_amdgcn_s_setprio(0);

    // additive key-padding bias
#pragma unroll
    for (int nk = 0; nk < 4; ++nk) {
      const f32x4 bv = *reinterpret_cast<const f32x4*>(&MB[b * 2048 + nt + nk * 16 + lhi * 4]);
#pragma unroll
      for (int mq = 0; mq < 2; ++mq)
#pragma unroll
        for (int j = 0; j < 4; ++j)
          st[nk][mq][j] += bv[j];
    }

    // online softmax: per lane, column q = mq*16+l15; 16 in-reg + xor16/xor32
    float al[2];
#pragma unroll
    for (int mq = 0; mq < 2; ++mq) {
      float tm = st[0][mq][0];
#pragma unroll
      for (int nk = 0; nk < 4; ++nk)
#pragma unroll
        for (int j = 0; j < 4; ++j) tm = fmaxf(tm, st[nk][mq][j]);
      tm = fmaxf(tm, __shfl_xor(tm, 16, 64));
      tm = fmaxf(tm, __shfl_xor(tm, 32, 64));
      const float mn = fmaxf(mrow[mq], tm);
      al[mq] = __builtin_amdgcn_exp2f(mrow[mq] - mn);
      mrow[mq] = mn;
      float rs = 0.f;
#pragma unroll
      for (int nk = 0; nk < 4; ++nk)
#pragma unroll
        for (int j = 0; j < 4; ++j) {
          const float p = __builtin_amdgcn_exp2f(st[nk][mq][j] - mn);
          st[nk][mq][j] = p;
          rs += p;
        }
      rs += __shfl_xor(rs, 16, 64);
      rs += __shfl_xor(rs, 32, 64);
      lsum[mq] = lsum[mq] * al[mq] + rs;
    }
    if (__any((al[0] != 1.f) || (al[1] != 1.f))) {
#pragma unroll
      for (int nd = 0; nd < 4; ++nd)
#pragma unroll
        for (int mq = 0; mq < 2; ++mq)
#pragma unroll
          for (int j = 0; j < 4; ++j) o[nd][mq][j] *= al[mq];
    }

    // P -> LDS (bf16, b64 writes; per-wave buffer, in-order DS pipe)
#pragma unroll
    for (int mq = 0; mq < 2; ++mq)
#pragma unroll
      for (int nk = 0; nk < 4; ++nk) {
        ushort4 pk;
        pk.x = bfc(st[nk][mq][0]); pk.y = bfc(st[nk][mq][1]);
        pk.z = bfc(st[nk][mq][2]); pk.w = bfc(st[nk][mq][3]);
        *reinterpret_cast<ushort4*>(&lsPt[w][mq * 16 + l15][nk * 16 + lhi * 4]) = pk;
      }

    // O^T += V^T P^T
    __builtin_amdgcn_s_setprio(1);
#pragma unroll
    for (int ks = 0; ks < 2; ++ks) {
      bf16x8 pb[2];
#pragma unroll
      for (int mq = 0; mq < 2; ++mq)
        pb[mq] = *reinterpret_cast<const bf16x8*>(
            &lsPt[w][mq * 16 + l15][ks * 32 + lhi * 8]);
#pragma unroll
      for (int nd = 0; nd < 4; ++nd) {
        const bf16x8 vt = *reinterpret_cast<const bf16x8*>(
            &lsV[cur][nd * 16 + l15][ks * 32 + lhi * 8]);
        o[nd][0] = __builtin_amdgcn_mfma_f32_16x16x32_bf16(vt, pb[0], o[nd][0], 0, 0, 0);
        o[nd][1] = __builtin_amdgcn_mfma_f32_16x16x32_bf16(vt, pb[1], o[nd][1], 0, 0, 0);
      }
    }
    __builtin_amdgcn_s_setprio(0);

    // write next tile into the other buffer (vmcnt wait covered by compute above);
    // all waves finished reading buf[cur^1] before the previous barrier.
    *reinterpret_cast<short8*>(&lsK[cur ^ 1][srow][scol]) = rk0;
    *reinterpret_cast<short8*>(&lsK[cur ^ 1][32 + srow][scol]) = rk1;
    *reinterpret_cast<short8*>(&lsV[cur ^ 1][srow][scol]) = rv0;
    *reinterpret_cast<short8*>(&lsV[cur ^ 1][32 + srow][scol]) = rv1;
    __syncthreads();
    cur ^= 1;
  }

  // epilogue: O[q][d], d = nd*16+lhi*4+j, q = mq*16+l15
#pragma unroll
  for (int mq = 0; mq < 2; ++mq) {
    const float inv = 1.f / lsum[mq];
#pragma unroll
    for (int nd = 0; nd < 4; ++nd) {
      ushort4 s4;
      s4.x = bfc(o[nd][mq][0] * inv); s4.y = bfc(o[nd][mq][1] * inv);
      s4.z = bfc(o[nd][mq][2] * inv); s4.w = bfc(o[nd][mq][3] * inv);
      *reinterpret_cast<ushort4*>(
          &O[(rowQ + mq * 16 + l15) * 1024 + hc + nd * 16 + lhi * 4]) = s4;
    }
  }
}

extern "C" void kernel_launch(void* const* d_in, const int* in_sizes, int n_in,
                              void* d_out, int out_size, void* d_ws, size_t ws_size,
                              hipStream_t stream) {
  const float* x_q = (const float*)d_in[0];
  const float* x_k = (const float*)d_in[1];
  const float* x_v = (const float*)d_in[2];
  const int*   msk = (const int*)d_in[3];
  const float* Wq  = (const float*)d_in[4];
  const float* bq  = (const float*)d_in[5];
  const float* Wk  = (const float*)d_in[6];
  const float* bk  = (const float*)d_in[7];
  const float* Wv  = (const float*)d_in[8];
  const float* bv  = (const float*)d_in[9];
  const float* Wo  = (const float*)d_in[10];
  const float* bo  = (const float*)d_in[11];

  const size_t NTOK = 4096, H = 1024;
  u16* xbf  = (u16*)d_ws;            // 3 * 4096*1024 bf16
  u16* wt   = xbf + 3 * NTOK * H;    // 4 * 1024*1024 bf16 (transposed weights)
  u16* qkv  = wt  + 4 * H * H;       // Q,K row-major; V slot holds Vt (transposed)
  u16* aout = qkv + 3 * NTOK * H;    // 4096*1024 bf16
  float* mb = (float*)(aout + NTOK * H);  // 4096 floats
  u16* vtb  = qkv + 2 * NTOK * H;    // Vt[b*1024 + c][s] (reuses V slot)

  k_cvt<<<dim3(4096), dim3(256), 0, stream>>>(x_q, xbf,              1048576);
  k_cvt<<<dim3(4096), dim3(256), 0, stream>>>(x_k, xbf + NTOK * H,   1048576);
  k_cvt<<<dim3(4096), dim3(256), 0, stream>>>(x_v, xbf + 2 * NTOK * H, 1048576);
  k_maskbias<<<dim3(16), dim3(256), 0, stream>>>(msk, mb, 4096);
  k_transcvt<<<dim3(32, 32), dim3(32, 8), 0, stream>>>(Wq, wt);
  k_transcvt<<<dim3(32, 32), dim3(32, 8), 0, stream>>>(Wk, wt + H * H);
  k_transcvt<<<dim3(32, 32), dim3(32, 8), 0, stream>>>(Wv, wt + 2 * H * H);
  k_transcvt<<<dim3(32, 32), dim3(32, 8), 0, stream>>>(Wo, wt + 3 * H * H);

  // Q,K,V = x{q,k,v} @ W{q,k,v} + b{q,k,v}; Q scaled by 0.125*log2(e) for exp2 softmax
  // z==2 (V) writes transposed into vtb.
  const float qscale = 0.125f * 1.4426950408889634f;
  k_gemm_bt<u16><<<dim3(32, 8, 3), dim3(256), 0, stream>>>(
      xbf, (long)(NTOK * H), wt, (long)(H * H), bq, bk, bv,
      qscale, 1.f, 1.f,
      qkv, (long)(NTOK * H), vtb, 4096, 1024, 1024);

  // attention (flat grid, XCD-grouped mapping inside)
  k_attn<<<dim3(512), dim3(256), 0, stream>>>(
      qkv, qkv + NTOK * H, vtb, mb, aout);

  // out = attn_out @ Wo + bo  (fp32 output)
  k_gemm_bt<float><<<dim3(32, 8, 1), dim3(256), 0, stream>>>(
      aout, 0L, wt + 3 * H * H, 0L, bo, bo, bo,
      1.f, 1.f, 1.f,
      (float*)d_out, 0L, nullptr, 4096, 1024, 1024);
}